// Round 5
// baseline (3609.532 us; speedup 1.0000x reference)
//
#include <hip/hip_runtime.h>
#include <hip/hip_cooperative_groups.h>

#define GRID   256
#define BLOCK  512
#define NWAVES (BLOCK / 64)
#define CHUNK  7813             // ceil(2e6 / 256)
#define SLOTS  16               // ceil(CHUNK / BLOCK)

typedef unsigned long long u64;
typedef unsigned int u32;

namespace cg = cooperative_groups;

// ---------------- r18: LLC-atomic aggregation, ONE RT per step ----------------
// Evidence: r13/r15/r17 all floor at ~5.8us/step regardless of hop-shaving
// (r17 removed every non-RT hop; dur unchanged, VALUBusy 13.6->54%) => chain
// is bound by TWO serial agent-scope round trips (partials->leader,
// totals->all). r16: >=256 readers/line serializes (FETCH 13.8->63.5MB).
// r18 moves the reduction INTO the LLC: per-round accumulator lines receive
// 256 blocks' partials as FIXED-POINT (2^28) integer atomicAdds (integer =>
// order-independent => bit-deterministic totals across runs AND graph
// replays), then a release-ordered count-add; every block polls count==256
// (1 poller/block + s_sleep backoff), acquire-fence, reads totals. Chain =
// half-RT adds + half-RT detect + 1 dependent read.
// Replay/poison safety: accumulators are PER-ROUND (never reused), zeroed
// in-kernel with agent-scope stores + one cooperative grid.sync before use.
// Layout per round (stride 48 u64 = 384B): A@+0B {num,sx}, B@+128B {sy,sz},
// C@+256B {cnt u32}; separate 128B lines bound same-line RMW serialization
// to 512/512/256 ops. In-set at fixed offset 256*48 (works for any T<=256;
// here T=240). Zeroing: block b zeroes round b (b<T); block GRID-1 zeroes
// the In set. Workspace use: 256*384+384 = 98,688 B.
// In-block f32 partial order is r13's exactly; only the cross-block combine
// changed (exact integer) -> output differs from the f32-sequential combine
// by ~1e-9-level quantization only.

#define SCALEF   268435456.0f          // 2^28
#define INV_SCALE (1.0 / 268435456.0)  // double

// exact fp32 constants as the fp32 reference sees them
#define C_NX   ((float)(-0.3420201433256687))
#define C_NY   ((float)( 0.9396926207859084))
#define C_DTF  ((float)(1.0 / 60.0 / 10.0))
#define C_HDT  ((float)(0.5 * (1.0 / 60.0 / 10.0)))
#define C_DTH  ((float)(-0.9396926207859084 * 0.1))
#define C_GYDT (-9.8f * (float)(1.0 / 60.0 / 10.0))

// ---------------- block reduction: NV values, result in thread 0 ----------------
template <int NV>
__device__ __forceinline__ void block_reduce(float* v, float* sm) {
  #pragma unroll
  for (int off = 32; off > 0; off >>= 1) {
    #pragma unroll
    for (int k = 0; k < NV; ++k) v[k] += __shfl_down(v[k], off, 64);
  }
  const int lane = threadIdx.x & 63;
  const int wid  = threadIdx.x >> 6;
  if (lane == 0) {
    #pragma unroll
    for (int k = 0; k < NV; ++k) sm[wid * NV + k] = v[k];
  }
  __syncthreads();
  if (threadIdx.x == 0) {
    #pragma unroll
    for (int w = 1; w < NWAVES; ++w) {
      #pragma unroll
      for (int k = 0; k < NV; ++k) v[k] += sm[w * NV + k];
    }
  }
  __syncthreads();
}

// ---------------- 3x3 helpers (row-major float[9], static indexing only) ----------------
__device__ __forceinline__ void mat3_mul(const float* A, const float* B, float* C) {
  #pragma unroll
  for (int i = 0; i < 3; ++i)
    #pragma unroll
    for (int j = 0; j < 3; ++j)
      C[i*3+j] = A[i*3+0]*B[0*3+j] + A[i*3+1]*B[1*3+j] + A[i*3+2]*B[2*3+j];
}
__device__ __forceinline__ void mat3_mul_bt(const float* A, const float* B, float* C) {
  #pragma unroll
  for (int i = 0; i < 3; ++i)
    #pragma unroll
    for (int j = 0; j < 3; ++j)
      C[i*3+j] = A[i*3+0]*B[j*3+0] + A[i*3+1]*B[j*3+1] + A[i*3+2]*B[j*3+2];
}
__device__ __forceinline__ void mat3_inv(const float* m, float* inv) {
  float A =  (m[4]*m[8] - m[5]*m[7]);
  float B = -(m[3]*m[8] - m[5]*m[6]);
  float C =  (m[3]*m[7] - m[4]*m[6]);
  float det = m[0]*A + m[1]*B + m[2]*C;
  float id = 1.0f / det;
  inv[0] = A * id;
  inv[1] = -(m[1]*m[8] - m[2]*m[7]) * id;
  inv[2] =  (m[1]*m[5] - m[2]*m[4]) * id;
  inv[3] = B * id;
  inv[4] =  (m[0]*m[8] - m[2]*m[6]) * id;
  inv[5] = -(m[0]*m[5] - m[2]*m[3]) * id;
  inv[6] = C * id;
  inv[7] = -(m[0]*m[7] - m[1]*m[6]) * id;
  inv[8] =  (m[0]*m[4] - m[1]*m[3]) * id;
}

__device__ __forceinline__ u64 agent_load_u64(const u64* p) {
  return __hip_atomic_load(p, __ATOMIC_RELAXED, __HIP_MEMORY_SCOPE_AGENT);
}
__device__ __forceinline__ u32 agent_load_u32(const u32* p) {
  return __hip_atomic_load(p, __ATOMIC_RELAXED, __HIP_MEMORY_SCOPE_AGENT);
}

__global__ __launch_bounds__(BLOCK, 2)
void sim_kernel(const float* __restrict__ xg,
                const float* __restrict__ mc_p,
                const float* __restrict__ itr_p,
                const float* __restrict__ iq_p,
                const float* __restrict__ iv_p,
                const float* __restrict__ kn_p,
                const float* __restrict__ mu_p,
                const float* __restrict__ ldp_p,
                const float* __restrict__ adp_p,
                float* __restrict__ out,
                u64* __restrict__ ws,
                int N, int T)
{
  const int tid  = threadIdx.x;
  const int bid  = blockIdx.x;
  const int lane = tid & 63;
  const int wid  = tid >> 6;

  __shared__ float s_redI[NWAVES * 6];   // init block_reduce scratch
  __shared__ float s_red[NWAVES * 4];    // per-step cross-wave partials
  __shared__ float s_tot[4];             // per-step totals
  __shared__ float s_in[6];              // inertia sums

  u64* inb = ws + (size_t)256 * 48;      // In set at fixed offset

  // ---- zero this run's accumulators (agent-scope -> lands at LLC) ----
  if (bid < T && tid < 5) {
    u64* rb = ws + (size_t)bid * 48;
    if (tid < 2)      __hip_atomic_store(rb + tid,      0ull, __ATOMIC_RELAXED, __HIP_MEMORY_SCOPE_AGENT);
    else if (tid < 4) __hip_atomic_store(rb + 14 + tid, 0ull, __ATOMIC_RELAXED, __HIP_MEMORY_SCOPE_AGENT);  // 16,17
    else              __hip_atomic_store((u32*)(rb + 32), 0u, __ATOMIC_RELAXED, __HIP_MEMORY_SCOPE_AGENT);
  }
  if (bid == GRID - 1 && tid < 7) {
    if (tid < 3)      __hip_atomic_store(inb + tid,      0ull, __ATOMIC_RELAXED, __HIP_MEMORY_SCOPE_AGENT);
    else if (tid < 6) __hip_atomic_store(inb + 13 + tid, 0ull, __ATOMIC_RELAXED, __HIP_MEMORY_SCOPE_AGENT); // 16,17,18
    else              __hip_atomic_store((u32*)(inb + 32), 0u, __ATOMIC_RELAXED, __HIP_MEMORY_SCOPE_AGENT);
  }
  cg::this_grid().sync();   // zeros visible before any atomicAdd (once)

  const float mc0 = mc_p[0], mc1 = mc_p[1], mc2 = mc_p[2];

  const int vstart = bid * CHUNK;
  int cl = N - vstart; if (cl > CHUNK) cl = CHUNK; if (cl < 0) cl = 0;

  // ---- stage this block's slice into REGISTERS; NaN-pad the tail ----
  const float NANF = __int_as_float(0x7fc00000);
  float xr0[SLOTS], xr1[SLOTS], xr2[SLOTS];
  #pragma unroll
  for (int s = 0; s < SLOTS; ++s) {
    const int i = tid + s * BLOCK;
    if (i < cl) {
      const float* p = xg + (size_t)(vstart + i) * 3;
      xr0[s] = p[0]; xr1[s] = p[1]; xr2[s] = p[2];
    } else {
      xr0[s] = NANF; xr1[s] = NANF; xr2[s] = NANF;
    }
  }

  // ---- inertia: in-block f32 partial (r13 order), cross-block exact int ----
  {
    float v6[6] = {0,0,0,0,0,0};
    #pragma unroll
    for (int s = 0; s < SLOTS; ++s) {
      if (tid + s * BLOCK < cl) {
        float r0 = xr0[s] - mc0, r1 = xr1[s] - mc1, r2 = xr2[s] - mc2;
        v6[0] += r0*r0; v6[1] += r1*r1; v6[2] += r2*r2;
        v6[3] += r0*r1; v6[4] += r0*r2; v6[5] += r1*r2;
      }
    }
    block_reduce<6>(v6, s_redI);
    if (tid == 0) {
      atomicAdd(inb + 0,  (u64)(long long)__float2ll_rn(v6[0] * SCALEF));
      atomicAdd(inb + 1,  (u64)(long long)__float2ll_rn(v6[1] * SCALEF));
      atomicAdd(inb + 2,  (u64)(long long)__float2ll_rn(v6[2] * SCALEF));
      atomicAdd(inb + 16, (u64)(long long)__float2ll_rn(v6[3] * SCALEF));
      atomicAdd(inb + 17, (u64)(long long)__float2ll_rn(v6[4] * SCALEF));
      atomicAdd(inb + 18, (u64)(long long)__float2ll_rn(v6[5] * SCALEF));
      __builtin_amdgcn_fence(__ATOMIC_RELEASE, "agent");
      atomicAdd((u32*)(inb + 32), 1u);
      int f = 0;
      for (;;) {
        u32 c = agent_load_u32((u32*)(inb + 32));
        if (c >= GRID) break;
        if ((++f & 1) == 0) __builtin_amdgcn_s_sleep(1);
      }
      __builtin_amdgcn_fence(__ATOMIC_ACQUIRE, "agent");
      s_in[0] = (float)((double)(long long)agent_load_u64(inb + 0)  * INV_SCALE);
      s_in[1] = (float)((double)(long long)agent_load_u64(inb + 1)  * INV_SCALE);
      s_in[2] = (float)((double)(long long)agent_load_u64(inb + 2)  * INV_SCALE);
      s_in[3] = (float)((double)(long long)agent_load_u64(inb + 16) * INV_SCALE);
      s_in[4] = (float)((double)(long long)agent_load_u64(inb + 17) * INV_SCALE);
      s_in[5] = (float)((double)(long long)agent_load_u64(inb + 18) * INV_SCALE);
    }
    __syncthreads();
  }
  float In[9];
  {
    float t0 = s_in[0], t1 = s_in[1], t2 = s_in[2];
    float trc = t0 + t1 + t2;
    In[0] = trc - t0; In[4] = trc - t1; In[8] = trc - t2;
    In[1] = -s_in[3]; In[3] = -s_in[3];
    In[2] = -s_in[4]; In[6] = -s_in[4];
    In[5] = -s_in[5]; In[7] = -s_in[5];
  }

  // ---- state: EVERY THREAD holds an identical copy (uniform evolution) ----
  float tr0 = itr_p[0], tr1 = itr_p[1], tr2 = itr_p[2];
  float q0 = iq_p[0], q1 = iq_p[1], q2 = iq_p[2], q3 = iq_p[3];
  {
    float n0 = sqrtf(q0*q0 + q1*q1 + q2*q2 + q3*q3);
    q0 /= n0; q1 /= n0; q2 /= n0; q3 /= n0;
  }
  float v0 = iv_p[0], v1 = iv_p[1], v2 = iv_p[2];
  float om0 = 0.f, om1 = 0.f, om2 = 0.f;
  const float knv = kn_p[0], muv = mu_p[0], ldv = ldp_p[0], adv = adp_p[0];
  const float inv_mass = 1.0f / (float)N;

  float Rm[9], Ii[9];
  float pa0, pa1, pa2, pb0, pb1, pb2, pca, pcb;
  int skip;

  {
    float qn = sqrtf(q0*q0 + q1*q1 + q2*q2 + q3*q3);
    float w = q0/qn, xq = q1/qn, yq = q2/qn, zq = q3/qn;
    Rm[0] = 1.f - 2.f*yq*yq - 2.f*zq*zq; Rm[1] = 2.f*xq*yq - 2.f*w*zq; Rm[2] = 2.f*xq*zq + 2.f*w*yq;
    Rm[3] = 2.f*xq*yq + 2.f*w*zq; Rm[4] = 1.f - 2.f*xq*xq - 2.f*zq*zq; Rm[5] = 2.f*yq*zq - 2.f*w*xq;
    Rm[6] = 2.f*xq*zq - 2.f*w*yq; Rm[7] = 2.f*yq*zq + 2.f*w*xq; Rm[8] = 1.f - 2.f*xq*xq - 2.f*yq*yq;
    pa0 = Rm[0]*C_NX + Rm[3]*C_NY;
    pa1 = Rm[1]*C_NX + Rm[4]*C_NY;
    pa2 = Rm[2]*C_NX + Rm[5]*C_NY;
    float w0 = C_NY*om2, w1 = -C_NX*om2, w2 = C_NX*om1 - C_NY*om0;   // = 0 exactly
    pb0 = Rm[0]*w0 + Rm[3]*w1 + Rm[6]*w2;
    pb1 = Rm[1]*w0 + Rm[4]*w1 + Rm[7]*w2;
    pb2 = Rm[2]*w0 + Rm[5]*w1 + Rm[8]*w2;
    pca = C_DTH - ((tr0 + mc0)*C_NX + (tr1 + mc1)*C_NY);
    pcb = -(v0*C_NX + v1*C_NY);
    skip = (om0 == 0.f && om1 == 0.f && om2 == 0.f && !(pcb > 0.f)) ? 1 : 0;
    float Tm[9]; mat3_mul(Rm, In, Tm);
    float Iw[9]; mat3_mul_bt(Tm, Rm, Iw);
    mat3_inv(Iw, Ii);
  }

  for (int t = 0; t < T; ++t) {
    float tn = 0.f, tx = 0.f, ty = 0.f, tz = 0.f;

    if (!skip) {
      u64* rb = ws + (size_t)t * 48;

      // ---- vertex loop: registers only; NaN pads self-mask ----
      float acc0 = 0.f, acc1 = 0.f, acc2 = 0.f, acc3 = 0.f;
      #pragma unroll
      for (int s = 0; s < SLOTS; ++s) {
        const float x0 = xr0[s], x1 = xr1[s], x2 = xr2[s];
        const float da = x0*pa0 + x1*pa1 + x2*pa2;
        const float db = x0*pb0 + x1*pb1 + x2*pb2;
        if (da < pca && db < pcb) {
          acc0 += 1.f; acc1 += x0; acc2 += x1; acc3 += x2;
        }
      }
      #pragma unroll
      for (int off = 32; off > 0; off >>= 1) {
        acc0 += __shfl_down(acc0, off, 64);
        acc1 += __shfl_down(acc1, off, 64);
        acc2 += __shfl_down(acc2, off, 64);
        acc3 += __shfl_down(acc3, off, 64);
      }
      if (lane == 0) {
        s_red[wid*4+0] = acc0; s_red[wid*4+1] = acc1;
        s_red[wid*4+2] = acc2; s_red[wid*4+3] = acc3;
      }
      __syncthreads();                       // B1: wave partials ready

      // ---- fire block partial into the LLC accumulators ----
      if (tid < 4) {
        float tw = s_red[tid];
        #pragma unroll
        for (int w2 = 1; w2 < NWAVES; ++w2) tw += s_red[w2*4 + tid];
        long long q = (tid == 0) ? (long long)tw : (long long)__float2ll_rn(tw * SCALEF);
        u64* ap = rb + ((tid < 2) ? tid : 14 + tid);   // words 0,1,16,17
        atomicAdd(ap, (u64)q);
      }
      if (tid == 0) {
        __builtin_amdgcn_fence(__ATOMIC_RELEASE, "agent");  // sums before cnt
        atomicAdd((u32*)(rb + 32), 1u);
        // ---- detect completion: ONE poller per block, backoff ----
        int f = 0;
        for (;;) {
          u32 c = agent_load_u32((u32*)(rb + 32));
          if (c >= GRID) break;
          if ((++f & 1) == 0) __builtin_amdgcn_s_sleep(1);
        }
        __builtin_amdgcn_fence(__ATOMIC_ACQUIRE, "agent");
        u64 a0 = agent_load_u64(rb + 0);
        u64 a1 = agent_load_u64(rb + 1);
        u64 b0 = agent_load_u64(rb + 16);
        u64 b1 = agent_load_u64(rb + 17);
        s_tot[0] = (float)(long long)a0;                              // exact count
        s_tot[1] = (float)((double)(long long)a1 * INV_SCALE);
        s_tot[2] = (float)((double)(long long)b0 * INV_SCALE);
        s_tot[3] = (float)((double)(long long)b1 * INV_SCALE);
      }
      __syncthreads();                       // B2: totals ready (also fences s_red reuse)
      tn = s_tot[0]; tx = s_tot[1]; ty = s_tot[2]; tz = s_tot[3];
    }

    // ---- physics + advance + plane recompute: ALL threads, uniform, bitwise ----
    {
      float dv0 = 0.f, dv1 = 0.f, dv2 = 0.f, dm0 = 0.f, dm1 = 0.f, dm2 = 0.f;
      if (tn > 0.0f) {
        float numf = fmaxf(tn, 1.0f);
        float ri0 = tx/numf, ri1 = ty/numf, ri2 = tz/numf;
        float Ri0 = Rm[0]*ri0 + Rm[1]*ri1 + Rm[2]*ri2;
        float Ri1 = Rm[3]*ri0 + Rm[4]*ri1 + Rm[5]*ri2;
        float Ri2 = Rm[6]*ri0 + Rm[7]*ri1 + Rm[8]*ri2;
        float vi0 = v0 + om1*Ri2 - om2*Ri1;
        float vi1 = v1 + om2*Ri0 - om0*Ri2;
        float vi2 = v2 + om0*Ri1 - om1*Ri0;
        float vdn = vi0*C_NX + vi1*C_NY;
        float vn0 = vdn*C_NX, vn1 = vdn*C_NY;        // vn2 == 0 exactly
        float vt0 = vi0 - vn0, vt1 = vi1 - vn1, vt2 = vi2;
        float nvn = sqrtf(vn0*vn0 + vn1*vn1);
        float nvt = sqrtf(vt0*vt0 + vt1*vt1 + vt2*vt2);
        float alpha = fmaxf(1.0f - muv*(1.0f + knv)*(nvn/(nvt + 1e-6f)), 0.0f);
        float dvi0 = (-knv*vn0 + alpha*vt0) - vi0;
        float dvi1 = (-knv*vn1 + alpha*vt1) - vi1;
        float dvi2 = (alpha*vt2) - vi2;
        float Cx[9] = {0.f, -Ri2, Ri1,  Ri2, 0.f, -Ri0,  -Ri1, Ri0, 0.f};
        float T2[9]; mat3_mul(Cx, Ii, T2);
        float T3[9]; mat3_mul(T2, Cx, T3);
        float Km[9];
        #pragma unroll
        for (int m = 0; m < 9; ++m) Km[m] = -T3[m];
        Km[0] += inv_mass; Km[4] += inv_mass; Km[8] += inv_mass;
        float Ki[9]; mat3_inv(Km, Ki);
        float J0 = Ki[0]*dvi0 + Ki[1]*dvi1 + Ki[2]*dvi2;
        float J1 = Ki[3]*dvi0 + Ki[4]*dvi1 + Ki[5]*dvi2;
        float J2 = Ki[6]*dvi0 + Ki[7]*dvi1 + Ki[8]*dvi2;
        dv0 = J0*inv_mass; dv1 = J1*inv_mass; dv2 = J2*inv_mass;
        float c0 = -Ri2*J1 + Ri1*J2;
        float c1 =  Ri2*J0 - Ri0*J2;
        float c2 = -Ri1*J0 + Ri0*J1;
        dm0 = Ii[0]*c0 + Ii[1]*c1 + Ii[2]*c2;
        dm1 = Ii[3]*c0 + Ii[4]*c1 + Ii[5]*c2;
        dm2 = Ii[6]*c0 + Ii[7]*c1 + Ii[8]*c2;
      }
      // advance (reference order, bitwise)
      v0 = v0*ldv + dv0;
      v1 = (v1 + C_GYDT)*ldv + dv1;
      v2 = v2*ldv + dv2;
      om0 = om0*adv + dm0; om1 = om1*adv + dm1; om2 = om2*adv + dm2;
      tr0 += C_DTF*v0; tr1 += C_DTF*v1; tr2 += C_DTF*v2;
      float wx = om0*C_HDT, wy = om1*C_HDT, wz = om2*C_HDT;
      float dq0 = -wx*q1 - wy*q2 - wz*q3;
      float dq1 =  wx*q0 + wy*q3 - wz*q2;
      float dq2 =  wy*q0 + wz*q1 - wx*q3;
      float dq3 =  wz*q0 + wx*q2 - wy*q1;
      q0 += dq0; q1 += dq1; q2 += dq2; q3 += dq3;
      float qn2 = sqrtf(q0*q0 + q1*q1 + q2*q2 + q3*q3);
      q0 /= qn2; q1 /= qn2; q2 /= qn2; q3 /= qn2;
      if (bid == 0 && tid == 0) {
        float* o = out + (size_t)t * 7;
        o[0] = tr0; o[1] = tr1; o[2] = tr2;
        o[3] = q0;  o[4] = q1;  o[5] = q2;  o[6] = q3;
      }
      // Rm(t+1), planes(t+1), skip(t+1), Ii(t+1)
      float qn = sqrtf(q0*q0 + q1*q1 + q2*q2 + q3*q3);
      float w = q0/qn, xq = q1/qn, yq = q2/qn, zq = q3/qn;
      Rm[0] = 1.f - 2.f*yq*yq - 2.f*zq*zq; Rm[1] = 2.f*xq*yq - 2.f*w*zq; Rm[2] = 2.f*xq*zq + 2.f*w*yq;
      Rm[3] = 2.f*xq*yq + 2.f*w*zq; Rm[4] = 1.f - 2.f*xq*xq - 2.f*zq*zq; Rm[5] = 2.f*yq*zq - 2.f*w*xq;
      Rm[6] = 2.f*xq*zq - 2.f*w*yq; Rm[7] = 2.f*yq*zq + 2.f*w*xq; Rm[8] = 1.f - 2.f*xq*xq - 2.f*yq*yq;
      pa0 = Rm[0]*C_NX + Rm[3]*C_NY;
      pa1 = Rm[1]*C_NX + Rm[4]*C_NY;
      pa2 = Rm[2]*C_NX + Rm[5]*C_NY;
      float w0 = C_NY*om2, w1 = -C_NX*om2, w2 = C_NX*om1 - C_NY*om0;
      pb0 = Rm[0]*w0 + Rm[3]*w1 + Rm[6]*w2;
      pb1 = Rm[1]*w0 + Rm[4]*w1 + Rm[7]*w2;
      pb2 = Rm[2]*w0 + Rm[5]*w1 + Rm[8]*w2;
      pca = C_DTH - ((tr0 + mc0)*C_NX + (tr1 + mc1)*C_NY);
      pcb = -(v0*C_NX + v1*C_NY);
      skip = (om0 == 0.f && om1 == 0.f && om2 == 0.f && !(pcb > 0.f)) ? 1 : 0;
      float Tm[9]; mat3_mul(Rm, In, Tm);
      float Iw[9]; mat3_mul_bt(Tm, Rm, Iw);
      mat3_inv(Iw, Ii);
    }
  }
}

extern "C" void kernel_launch(void* const* d_in, const int* in_sizes, int n_in,
                              void* d_out, int out_size, void* d_ws, size_t ws_size,
                              hipStream_t stream) {
  const float* x   = (const float*)d_in[0];
  const float* mc  = (const float*)d_in[1];
  const float* itr = (const float*)d_in[2];
  const float* iq  = (const float*)d_in[3];
  const float* iv  = (const float*)d_in[4];
  const float* kn  = (const float*)d_in[5];
  const float* mu  = (const float*)d_in[6];
  const float* ldp = (const float*)d_in[7];
  const float* adp = (const float*)d_in[8];
  float* out = (float*)d_out;
  u64* ws  = (u64*)d_ws;
  int N = in_sizes[0] / 3;
  int T = out_size / 7;

  void* args[] = {(void*)&x, (void*)&mc, (void*)&itr, (void*)&iq, (void*)&iv,
                  (void*)&kn, (void*)&mu, (void*)&ldp, (void*)&adp,
                  (void*)&out, (void*)&ws, (void*)&N, (void*)&T};
  // cooperative launch: co-residency + the ONE init grid.sync
  hipLaunchCooperativeKernel((void*)sim_kernel, dim3(GRID), dim3(BLOCK),
                             args, 0, stream);
}

// Round 6
// 1896.470 us; speedup vs baseline: 1.9033x; 1.9033x over previous
//
#include <hip/hip_runtime.h>

#define GRID    256
#define BLOCK   512
#define NWAVES  (BLOCK / 64)
#define CHUNK   7813            // ceil(2e6 / 256)
#define SLOTS   16              // ceil(CHUNK / BLOCK)
#define NREPR   64              // REQ replica lines
#define CAP     96              // max candidates per block
#define CSTRIDE 296             // 1 count word + 3*CAP data words, padded
#define CAPTOT  4096            // leader LDS candidate cache capacity
#define EPSB    0.03f           // scan band width (d-units)

#define MODE_SCAN 1u
#define MODE_FULL 2u
#define MODE_DONE 3u

typedef unsigned long long u64;
typedef unsigned int u32;

// ---------------- r19: candidate-cache protocol ----------------
// Evidence: r13/r15/r17 floor at ~5.8us/step = 2 agent-scope RTs x 240 full-
// grid rounds (r17 removed every non-RT hop; flat). r16/r18: >=256 same-line
// readers or RMWs serialize at the coherence point. absmax==0.0 survived
// r18's 2^-28 fixed-point quantization => contact sets are TINY (f32-exact
// sums). r19 stops running grid-wide rounds for ~1e2-vertex work: blocks
// publish a conservative candidate superset {x : x.a_r < ca_r + EPS} at
// rare refreshes; the leader caches candidates in LDS and steps LOCALLY
// (~0.3us/step, zero comms), verifying per step that
//   ca(t) + |a(t)-a_r|*maxX <= ca_r + EPS   (maxX = max |x|, exact bound)
// so candidate-mode results are bit-equal to full-set tests. Violation ->
// refresh. Per-block overflow (cnt > CAP: big contact set) -> bounded
// fallback: r13-style FULL rounds (REQ planes -> 4-word partial publish ->
// leader gather) at the proven ~6us/step pace, rescan every 4 steps.
// Protocol: servants poll ONE replica REQ line (64 replicas, tid<16 pollers;
// fan-in ~= r13's verified density). All published words are deterministic
// functions of the input (candidate compaction in slot-major ballot order;
// state evolution leader-serial) => tagged words (tag = rrnd, init tag
// 0xC0FFEE; poison 0xAAAAAAAA never matches) are graph-replay safe: a stale
// word from a prior replay is bitwise identical. Single-buffer reuse is WAR-
// safe: leader consumes round r fully before issuing REQ(r+1), and servants
// write round r+1 only after reading REQ(r+1).
// ws use (u64): req 1024 | part 1024 | bufI 1792 | cand 256*296 = 75776
//   => 79,616 u64 = 622 KB.

__device__ __forceinline__ u64 rec_load(const u64* p) {
  return __hip_atomic_load(p, __ATOMIC_RELAXED, __HIP_MEMORY_SCOPE_AGENT);
}
__device__ __forceinline__ void rec_store(u64* p, u64 v) {
  __hip_atomic_store(p, v, __ATOMIC_RELAXED, __HIP_MEMORY_SCOPE_AGENT);
}
__device__ __forceinline__ u64 rec_pack(float f, unsigned tag) {
  return (u64)__float_as_uint(f) | ((u64)tag << 32);
}
__device__ __forceinline__ u64 rec_pack_u(u32 v, unsigned tag) {
  return (u64)v | ((u64)tag << 32);
}

// exact fp32 constants as the fp32 reference sees them
#define C_NX   ((float)(-0.3420201433256687))
#define C_NY   ((float)( 0.9396926207859084))
#define C_DTF  ((float)(1.0 / 60.0 / 10.0))
#define C_HDT  ((float)(0.5 * (1.0 / 60.0 / 10.0)))
#define C_DTH  ((float)(-0.9396926207859084 * 0.1))
#define C_GYDT (-9.8f * (float)(1.0 / 60.0 / 10.0))

// ---------------- 3x3 helpers (row-major float[9], static indexing only) ----------------
__device__ __forceinline__ void mat3_mul(const float* A, const float* B, float* C) {
  #pragma unroll
  for (int i = 0; i < 3; ++i)
    #pragma unroll
    for (int j = 0; j < 3; ++j)
      C[i*3+j] = A[i*3+0]*B[0*3+j] + A[i*3+1]*B[1*3+j] + A[i*3+2]*B[2*3+j];
}
__device__ __forceinline__ void mat3_mul_bt(const float* A, const float* B, float* C) {
  #pragma unroll
  for (int i = 0; i < 3; ++i)
    #pragma unroll
    for (int j = 0; j < 3; ++j)
      C[i*3+j] = A[i*3+0]*B[j*3+0] + A[i*3+1]*B[j*3+1] + A[i*3+2]*B[j*3+2];
}
__device__ __forceinline__ void mat3_inv(const float* m, float* inv) {
  float A =  (m[4]*m[8] - m[5]*m[7]);
  float B = -(m[3]*m[8] - m[5]*m[6]);
  float C =  (m[3]*m[7] - m[4]*m[6]);
  float det = m[0]*A + m[1]*B + m[2]*C;
  float id = 1.0f / det;
  inv[0] = A * id;
  inv[1] = -(m[1]*m[8] - m[2]*m[7]) * id;
  inv[2] =  (m[1]*m[5] - m[2]*m[4]) * id;
  inv[3] = B * id;
  inv[4] =  (m[0]*m[8] - m[2]*m[6]) * id;
  inv[5] = -(m[0]*m[5] - m[2]*m[3]) * id;
  inv[6] = C * id;
  inv[7] = -(m[0]*m[7] - m[1]*m[6]) * id;
  inv[8] =  (m[0]*m[4] - m[1]*m[3]) * id;
}

// ---------------- deterministic candidate scan + publish (any block) ----------------
__device__ __forceinline__ void scan_publish(
    const float* xr0, const float* xr1, const float* xr2,
    float A0, float A1, float A2, float THR,
    unsigned rrnd, u64* region, u32* s_wc /*SLOTS*NWAVES*/)
{
  const int tid = threadIdx.x, lane = tid & 63, wid = tid >> 6;
  #pragma unroll
  for (int s = 0; s < SLOTS; ++s) {
    float da = xr0[s]*A0 + xr1[s]*A1 + xr2[s]*A2;   // NaN pads -> false
    u64 m = __ballot(da < THR);
    if (lane == 0) s_wc[s*NWAVES + wid] = (u32)__popcll(m);
  }
  __syncthreads();
  int runbase = 0;
  #pragma unroll
  for (int s = 0; s < SLOTS; ++s) {
    int wb = 0, tot = 0;
    #pragma unroll
    for (int w = 0; w < NWAVES; ++w) {
      u32 c = s_wc[s*NWAVES + w];
      if (w < wid) wb += (int)c;
      tot += (int)c;
    }
    const float x0 = xr0[s], x1 = xr1[s], x2 = xr2[s];
    const float da = x0*A0 + x1*A1 + x2*A2;
    const bool pred = (da < THR);
    const u64 m = __ballot(pred);
    if (pred) {
      int pos = runbase + wb + (int)__popcll(m & ((1ull << lane) - 1ull));
      if (pos < CAP) {
        u64* dp = region + 1 + 3*(size_t)pos;
        rec_store(dp + 0, rec_pack(x0, rrnd));
        rec_store(dp + 1, rec_pack(x1, rrnd));
        rec_store(dp + 2, rec_pack(x2, rrnd));
      }
    }
    runbase += tot;
  }
  if (tid == 0) rec_store(region, rec_pack_u((u32)runbase, rrnd));
  __syncthreads();   // s_wc reusable
}

// ---------------- full-plane test + 4-word partial publish (any block) ----------------
__device__ __forceinline__ void full_publish(
    const float* xr0, const float* xr1, const float* xr2,
    float A0, float A1, float A2, float CAv,
    float B0, float B1, float B2, float CBv,
    unsigned rrnd, u64* part, int bid, float* s_red)
{
  const int tid = threadIdx.x, lane = tid & 63, wid = tid >> 6;
  float a0 = 0.f, a1 = 0.f, a2 = 0.f, a3 = 0.f;
  #pragma unroll
  for (int s = 0; s < SLOTS; ++s) {
    const float x0 = xr0[s], x1 = xr1[s], x2 = xr2[s];
    const float da = x0*A0 + x1*A1 + x2*A2;
    const float db = x0*B0 + x1*B1 + x2*B2;
    if (da < CAv && db < CBv) { a0 += 1.f; a1 += x0; a2 += x1; a3 += x2; }
  }
  #pragma unroll
  for (int off = 32; off > 0; off >>= 1) {
    a0 += __shfl_down(a0, off, 64);
    a1 += __shfl_down(a1, off, 64);
    a2 += __shfl_down(a2, off, 64);
    a3 += __shfl_down(a3, off, 64);
  }
  if (lane == 0) {
    s_red[wid*4+0] = a0; s_red[wid*4+1] = a1;
    s_red[wid*4+2] = a2; s_red[wid*4+3] = a3;
  }
  __syncthreads();
  if (tid < 4) {
    float tw = s_red[tid];
    #pragma unroll
    for (int w = 1; w < NWAVES; ++w) tw += s_red[w*4 + tid];
    rec_store(part + (size_t)tid * GRID + bid, rec_pack(tw, rrnd));
  }
  __syncthreads();   // s_red reusable
}

// ---------------- leader: one physics step (tid0 only) ----------------
__device__ __forceinline__ void leader_step(
    float tn, float tx, float ty, float tz,
    float& tr0, float& tr1, float& tr2,
    float& q0, float& q1, float& q2, float& q3,
    float& v0, float& v1, float& v2,
    float& om0, float& om1, float& om2,
    float (&Rm)[9], const float (&In)[9],
    float knv, float muv, float ldv, float adv, float inv_mass,
    float mc0, float mc1,
    float* s_plane, float* outp)
{
  float dv0 = 0.f, dv1 = 0.f, dv2 = 0.f, dm0 = 0.f, dm1 = 0.f, dm2 = 0.f;
  if (tn > 0.0f) {
    float Tm[9]; mat3_mul(Rm, In, Tm);
    float Iw[9]; mat3_mul_bt(Tm, Rm, Iw);
    float Ii[9]; mat3_inv(Iw, Ii);
    float numf = fmaxf(tn, 1.0f);
    float ri0 = tx/numf, ri1 = ty/numf, ri2 = tz/numf;
    float Ri0 = Rm[0]*ri0 + Rm[1]*ri1 + Rm[2]*ri2;
    float Ri1 = Rm[3]*ri0 + Rm[4]*ri1 + Rm[5]*ri2;
    float Ri2 = Rm[6]*ri0 + Rm[7]*ri1 + Rm[8]*ri2;
    float vi0 = v0 + om1*Ri2 - om2*Ri1;
    float vi1 = v1 + om2*Ri0 - om0*Ri2;
    float vi2 = v2 + om0*Ri1 - om1*Ri0;
    float vdn = vi0*C_NX + vi1*C_NY;
    float vn0 = vdn*C_NX, vn1 = vdn*C_NY;            // vn2 == 0 exactly
    float vt0 = vi0 - vn0, vt1 = vi1 - vn1, vt2 = vi2;
    float nvn = sqrtf(vn0*vn0 + vn1*vn1);
    float nvt = sqrtf(vt0*vt0 + vt1*vt1 + vt2*vt2);
    float alpha = fmaxf(1.0f - muv*(1.0f + knv)*(nvn/(nvt + 1e-6f)), 0.0f);
    float dvi0 = (-knv*vn0 + alpha*vt0) - vi0;
    float dvi1 = (-knv*vn1 + alpha*vt1) - vi1;
    float dvi2 = (alpha*vt2) - vi2;
    float Cx[9] = {0.f, -Ri2, Ri1,  Ri2, 0.f, -Ri0,  -Ri1, Ri0, 0.f};
    float T2[9]; mat3_mul(Cx, Ii, T2);
    float T3[9]; mat3_mul(T2, Cx, T3);
    float Km[9];
    #pragma unroll
    for (int m = 0; m < 9; ++m) Km[m] = -T3[m];
    Km[0] += inv_mass; Km[4] += inv_mass; Km[8] += inv_mass;
    float Ki[9]; mat3_inv(Km, Ki);
    float J0 = Ki[0]*dvi0 + Ki[1]*dvi1 + Ki[2]*dvi2;
    float J1 = Ki[3]*dvi0 + Ki[4]*dvi1 + Ki[5]*dvi2;
    float J2 = Ki[6]*dvi0 + Ki[7]*dvi1 + Ki[8]*dvi2;
    dv0 = J0*inv_mass; dv1 = J1*inv_mass; dv2 = J2*inv_mass;
    float c0 = -Ri2*J1 + Ri1*J2;
    float c1 =  Ri2*J0 - Ri0*J2;
    float c2 = -Ri1*J0 + Ri0*J1;
    dm0 = Ii[0]*c0 + Ii[1]*c1 + Ii[2]*c2;
    dm1 = Ii[3]*c0 + Ii[4]*c1 + Ii[5]*c2;
    dm2 = Ii[6]*c0 + Ii[7]*c1 + Ii[8]*c2;
  }
  v0 = v0*ldv + dv0;
  v1 = (v1 + C_GYDT)*ldv + dv1;
  v2 = v2*ldv + dv2;
  om0 = om0*adv + dm0; om1 = om1*adv + dm1; om2 = om2*adv + dm2;
  tr0 += C_DTF*v0; tr1 += C_DTF*v1; tr2 += C_DTF*v2;
  float wx = om0*C_HDT, wy = om1*C_HDT, wz = om2*C_HDT;
  float dq0 = -wx*q1 - wy*q2 - wz*q3;
  float dq1 =  wx*q0 + wy*q3 - wz*q2;
  float dq2 =  wy*q0 + wz*q1 - wx*q3;
  float dq3 =  wz*q0 + wx*q2 - wy*q1;
  q0 += dq0; q1 += dq1; q2 += dq2; q3 += dq3;
  float qn2 = sqrtf(q0*q0 + q1*q1 + q2*q2 + q3*q3);
  q0 /= qn2; q1 /= qn2; q2 /= qn2; q3 /= qn2;
  outp[0] = tr0; outp[1] = tr1; outp[2] = tr2;
  outp[3] = q0;  outp[4] = q1;  outp[5] = q2;  outp[6] = q3;
  // Rm(t+1) + planes(t+1)
  float qn = sqrtf(q0*q0 + q1*q1 + q2*q2 + q3*q3);
  float w = q0/qn, xq = q1/qn, yq = q2/qn, zq = q3/qn;
  Rm[0] = 1.f - 2.f*yq*yq - 2.f*zq*zq; Rm[1] = 2.f*xq*yq - 2.f*w*zq; Rm[2] = 2.f*xq*zq + 2.f*w*yq;
  Rm[3] = 2.f*xq*yq + 2.f*w*zq; Rm[4] = 1.f - 2.f*xq*xq - 2.f*zq*zq; Rm[5] = 2.f*yq*zq - 2.f*w*xq;
  Rm[6] = 2.f*xq*zq - 2.f*w*yq; Rm[7] = 2.f*yq*zq + 2.f*w*xq; Rm[8] = 1.f - 2.f*xq*xq - 2.f*yq*yq;
  s_plane[0] = Rm[0]*C_NX + Rm[3]*C_NY;
  s_plane[1] = Rm[1]*C_NX + Rm[4]*C_NY;
  s_plane[2] = Rm[2]*C_NX + Rm[5]*C_NY;
  float w0 = C_NY*om2, w1 = -C_NX*om2, w2 = C_NX*om1 - C_NY*om0;
  s_plane[4] = Rm[0]*w0 + Rm[3]*w1 + Rm[6]*w2;
  s_plane[5] = Rm[1]*w0 + Rm[4]*w1 + Rm[7]*w2;
  s_plane[6] = Rm[2]*w0 + Rm[5]*w1 + Rm[8]*w2;
  s_plane[3] = C_DTH - ((tr0 + mc0)*C_NX + (tr1 + mc1)*C_NY);
  s_plane[7] = -(v0*C_NX + v1*C_NY);
}

__global__ __launch_bounds__(BLOCK, 2)
void sim_kernel(const float* __restrict__ xg,
                const float* __restrict__ mc_p,
                const float* __restrict__ itr_p,
                const float* __restrict__ iq_p,
                const float* __restrict__ iv_p,
                const float* __restrict__ kn_p,
                const float* __restrict__ mu_p,
                const float* __restrict__ ldp_p,
                const float* __restrict__ adp_p,
                float* __restrict__ out,
                u64* __restrict__ ws,
                int N, int T)
{
  const int tid  = threadIdx.x;
  const int bid  = blockIdx.x;
  const int lane = tid & 63;
  const int wid  = tid >> 6;

  __shared__ float s_redI[NWAVES * 7];
  __shared__ float s_red[NWAVES * 4];
  __shared__ float s_plane[8];        // a0,a1,a2,ca, b0,b1,b2,cb
  __shared__ u32   s_reqw[16];
  __shared__ u32   s_cnt[GRID];
  __shared__ u32   s_wc[SLOTS * NWAVES];
  __shared__ u32   s_act;
  __shared__ u32   s_total;

  extern __shared__ float dyn[];      // leader candidate cache (64 KB)
  float* cx = dyn;
  float* cy = dyn + CAPTOT;
  float* cz = dyn + 2 * CAPTOT;
  u32*   cmap = (u32*)(dyn + 3 * CAPTOT);

  // workspace layout (u64)
  u64* req  = ws;                       // NREPR*16          = 1024
  u64* part = ws + 1024;                // 4*GRID            = 1024
  u64* bufI = ws + 2048;                // 7*GRID            = 1792
  u64* cand = ws + 3840;                // GRID*CSTRIDE      = 75776

  const float mc0 = mc_p[0], mc1 = mc_p[1], mc2 = mc_p[2];

  const int vstart = bid * CHUNK;
  int cl = N - vstart; if (cl > CHUNK) cl = CHUNK; if (cl < 0) cl = 0;

  // ---- stage slice into registers; NaN-pad the tail ----
  const float NANF = __int_as_float(0x7fc00000);
  float xr0[SLOTS], xr1[SLOTS], xr2[SLOTS];
  #pragma unroll
  for (int s = 0; s < SLOTS; ++s) {
    const int i = tid + s * BLOCK;
    if (i < cl) {
      const float* p = xg + (size_t)(vstart + i) * 3;
      xr0[s] = p[0]; xr1[s] = p[1]; xr2[s] = p[2];
    } else {
      xr0[s] = NANF; xr1[s] = NANF; xr2[s] = NANF;
    }
  }

  // ---- inertia + maxX partials: publish 7 tagged words per block ----
  {
    float v7[7] = {0,0,0,0,0,0,0};
    #pragma unroll
    for (int s = 0; s < SLOTS; ++s) {
      if (tid + s * BLOCK < cl) {
        float r0 = xr0[s] - mc0, r1 = xr1[s] - mc1, r2 = xr2[s] - mc2;
        v7[0] += r0*r0; v7[1] += r1*r1; v7[2] += r2*r2;
        v7[3] += r0*r1; v7[4] += r0*r2; v7[5] += r1*r2;
        float n2 = xr0[s]*xr0[s] + xr1[s]*xr1[s] + xr2[s]*xr2[s];
        v7[6] = fmaxf(v7[6], n2);
      }
    }
    #pragma unroll
    for (int off = 32; off > 0; off >>= 1) {
      #pragma unroll
      for (int k = 0; k < 6; ++k) v7[k] += __shfl_down(v7[k], off, 64);
      v7[6] = fmaxf(v7[6], __shfl_down(v7[6], off, 64));
    }
    if (lane == 0) {
      #pragma unroll
      for (int k = 0; k < 7; ++k) s_redI[wid * 7 + k] = v7[k];
    }
    __syncthreads();
    if (tid == 0) {
      float t7[7];
      #pragma unroll
      for (int k = 0; k < 7; ++k) t7[k] = s_redI[k];
      #pragma unroll
      for (int w = 1; w < NWAVES; ++w) {
        #pragma unroll
        for (int k = 0; k < 6; ++k) t7[k] += s_redI[w * 7 + k];
        t7[6] = fmaxf(t7[6], s_redI[w * 7 + 6]);
      }
      #pragma unroll
      for (int k = 0; k < 7; ++k)
        rec_store(bufI + (size_t)k * GRID + bid, rec_pack(t7[k], 0xC0FFEEu));
    }
    __syncthreads();
  }

  // ======================= SERVANTS (bid != 0) =======================
  if (bid != 0) {
    unsigned rrnd = 1;
    for (;;) {
      if (tid < 16) {
        const u64* rl = req + (size_t)(bid & (NREPR - 1)) * 16 + tid;
        u64 r; int f = 0;
        for (;;) {
          r = rec_load(rl);
          if ((unsigned)(r >> 32) == rrnd) break;
          if ((++f & 31) == 0) __builtin_amdgcn_s_sleep(4);
        }
        s_reqw[tid] = (u32)r;
      }
      __syncthreads();
      const u32 mode = s_reqw[9];
      if (mode == MODE_DONE) return;
      const float A0 = __uint_as_float(s_reqw[0]);
      const float A1 = __uint_as_float(s_reqw[1]);
      const float A2 = __uint_as_float(s_reqw[2]);
      if (mode == MODE_SCAN) {
        const float THR = __uint_as_float(s_reqw[8]);
        scan_publish(xr0, xr1, xr2, A0, A1, A2, THR, rrnd,
                     cand + (size_t)bid * CSTRIDE, s_wc);
      } else {
        const float CAv = __uint_as_float(s_reqw[3]);
        const float B0 = __uint_as_float(s_reqw[4]);
        const float B1 = __uint_as_float(s_reqw[5]);
        const float B2 = __uint_as_float(s_reqw[6]);
        const float CBv = __uint_as_float(s_reqw[7]);
        full_publish(xr0, xr1, xr2, A0, A1, A2, CAv, B0, B1, B2, CBv,
                     rrnd, part, bid, s_red);
      }
      ++rrnd;
      __syncthreads();   // s_reqw safe for next poll
    }
  }

  // ======================= LEADER (bid == 0) =======================
  // ---- gather In + maxX (256-lane tagged poll; 1 reader/word) ----
  float In[9];
  float maxX = 0.f;
  {
    float g7[7] = {0,0,0,0,0,0,0};
    if (tid < GRID) {
      u64 r[7]; int f = 0;
      for (;;) {
        #pragma unroll
        for (int k = 0; k < 7; ++k) r[k] = rec_load(bufI + (size_t)k * GRID + tid);
        bool ok = true;
        #pragma unroll
        for (int k = 0; k < 7; ++k) ok &= ((unsigned)(r[k] >> 32) == 0xC0FFEEu);
        if (ok) break;
        if ((++f & 15) == 0) __builtin_amdgcn_s_sleep(1);
      }
      #pragma unroll
      for (int k = 0; k < 7; ++k) g7[k] = __uint_as_float((unsigned)r[k]);
    }
    #pragma unroll
    for (int off = 32; off > 0; off >>= 1) {
      #pragma unroll
      for (int k = 0; k < 6; ++k) g7[k] += __shfl_down(g7[k], off, 64);
      g7[6] = fmaxf(g7[6], __shfl_down(g7[6], off, 64));
    }
    if (lane == 0) {
      #pragma unroll
      for (int k = 0; k < 7; ++k) s_redI[wid * 7 + k] = g7[k];
    }
    __syncthreads();
    float t7[7];
    #pragma unroll
    for (int k = 0; k < 7; ++k) t7[k] = s_redI[k];
    #pragma unroll
    for (int w = 1; w < NWAVES; ++w) {
      #pragma unroll
      for (int k = 0; k < 6; ++k) t7[k] += s_redI[w * 7 + k];
      t7[6] = fmaxf(t7[6], s_redI[w * 7 + 6]);
    }
    float trc = t7[0] + t7[1] + t7[2];
    In[0] = trc - t7[0]; In[4] = trc - t7[1]; In[8] = trc - t7[2];
    In[1] = -t7[3]; In[3] = -t7[3];
    In[2] = -t7[4]; In[6] = -t7[4];
    In[5] = -t7[5]; In[7] = -t7[5];
    maxX = sqrtf(t7[6]);
  }

  // ---- leader state (tid0 regs) + planes(0) ----
  float tr0, tr1, tr2, q0, q1, q2, q3, v0, v1, v2, om0, om1, om2;
  float Rm[9];
  const float knv = kn_p[0], muv = mu_p[0], ldv = ldp_p[0], adv = adp_p[0];
  const float inv_mass = 1.0f / (float)N;
  if (tid == 0) {
    tr0 = itr_p[0]; tr1 = itr_p[1]; tr2 = itr_p[2];
    q0 = iq_p[0]; q1 = iq_p[1]; q2 = iq_p[2]; q3 = iq_p[3];
    float n0 = sqrtf(q0*q0 + q1*q1 + q2*q2 + q3*q3);
    q0 /= n0; q1 /= n0; q2 /= n0; q3 /= n0;
    v0 = iv_p[0]; v1 = iv_p[1]; v2 = iv_p[2];
    om0 = 0.f; om1 = 0.f; om2 = 0.f;
    float qn = sqrtf(q0*q0 + q1*q1 + q2*q2 + q3*q3);
    float w = q0/qn, xq = q1/qn, yq = q2/qn, zq = q3/qn;
    Rm[0] = 1.f - 2.f*yq*yq - 2.f*zq*zq; Rm[1] = 2.f*xq*yq - 2.f*w*zq; Rm[2] = 2.f*xq*zq + 2.f*w*yq;
    Rm[3] = 2.f*xq*yq + 2.f*w*zq; Rm[4] = 1.f - 2.f*xq*xq - 2.f*zq*zq; Rm[5] = 2.f*yq*zq - 2.f*w*xq;
    Rm[6] = 2.f*xq*zq - 2.f*w*yq; Rm[7] = 2.f*yq*zq + 2.f*w*xq; Rm[8] = 1.f - 2.f*xq*xq - 2.f*yq*yq;
    s_plane[0] = Rm[0]*C_NX + Rm[3]*C_NY;
    s_plane[1] = Rm[1]*C_NX + Rm[4]*C_NY;
    s_plane[2] = Rm[2]*C_NX + Rm[5]*C_NY;
    float w0 = C_NY*om2, w1 = -C_NX*om2, w2 = C_NX*om1 - C_NY*om0;   // = 0 exactly
    s_plane[4] = Rm[0]*w0 + Rm[3]*w1 + Rm[6]*w2;
    s_plane[5] = Rm[1]*w0 + Rm[4]*w1 + Rm[7]*w2;
    s_plane[6] = Rm[2]*w0 + Rm[5]*w1 + Rm[8]*w2;
    s_plane[3] = C_DTH - ((tr0 + mc0)*C_NX + (tr1 + mc1)*C_NY);
    s_plane[7] = -(v0*C_NX + v1*C_NY);
  }
  __syncthreads();

  unsigned rrnd = 1;
  int t = 0;
  int fullsteps = 0;
  float ar0, ar1, ar2, thr_r;   // tid0: scan reference

  for (;;) {
    if (t >= T) {
      // ---- DONE ----
      if (tid == 0) { s_reqw[9] = MODE_DONE; }
      __syncthreads();
      for (int i = tid; i < NREPR * 16; i += BLOCK) {
        u32 pay = ((i & 15) == 9) ? MODE_DONE : 0u;
        rec_store(req + i, rec_pack_u(pay, rrnd));
      }
      return;
    }

    if (fullsteps > 0) {
      // ---------- one FULL round (r13-class fallback) ----------
      if (tid == 0) {
        #pragma unroll
        for (int k = 0; k < 8; ++k) s_reqw[k] = __float_as_uint(s_plane[k] * 1.0f);
        // NOTE: order in s_plane is a0,a1,a2,ca,b0,b1,b2,cb == REQ words 0..7
        s_reqw[8] = 0u; s_reqw[9] = MODE_FULL;
        #pragma unroll
        for (int k = 10; k < 16; ++k) s_reqw[k] = 0u;
      }
      __syncthreads();
      for (int i = tid; i < NREPR * 16; i += BLOCK)
        rec_store(req + i, rec_pack_u(s_reqw[i & 15], rrnd));
      // self partial
      full_publish(xr0, xr1, xr2,
                   s_plane[0], s_plane[1], s_plane[2], s_plane[3],
                   s_plane[4], s_plane[5], s_plane[6], s_plane[7],
                   rrnd, part, 0, s_red);
      // gather 256 partials
      float f0 = 0.f, f1 = 0.f, f2 = 0.f, f3 = 0.f;
      if (tid < GRID) {
        const u64* pp = part + tid;
        u64 r0, r1, r2, r3; int fl = 0;
        for (;;) {
          r0 = rec_load(pp + 0 * GRID);
          r1 = rec_load(pp + 1 * GRID);
          r2 = rec_load(pp + 2 * GRID);
          r3 = rec_load(pp + 3 * GRID);
          if (((unsigned)(r0 >> 32) == rrnd) && ((unsigned)(r1 >> 32) == rrnd) &&
              ((unsigned)(r2 >> 32) == rrnd) && ((unsigned)(r3 >> 32) == rrnd)) break;
          if ((++fl & 15) == 0) __builtin_amdgcn_s_sleep(1);
        }
        f0 = __uint_as_float((unsigned)r0);
        f1 = __uint_as_float((unsigned)r1);
        f2 = __uint_as_float((unsigned)r2);
        f3 = __uint_as_float((unsigned)r3);
      }
      #pragma unroll
      for (int off = 32; off > 0; off >>= 1) {
        f0 += __shfl_down(f0, off, 64);
        f1 += __shfl_down(f1, off, 64);
        f2 += __shfl_down(f2, off, 64);
        f3 += __shfl_down(f3, off, 64);
      }
      if (lane == 0) {
        s_red[wid*4+0] = f0; s_red[wid*4+1] = f1;
        s_red[wid*4+2] = f2; s_red[wid*4+3] = f3;
      }
      __syncthreads();
      if (tid == 0) {
        float tn = s_red[0], tx = s_red[1], ty = s_red[2], tz = s_red[3];
        #pragma unroll
        for (int w = 1; w < NWAVES; ++w) {
          tn += s_red[w*4+0]; tx += s_red[w*4+1];
          ty += s_red[w*4+2]; tz += s_red[w*4+3];
        }
        leader_step(tn, tx, ty, tz, tr0, tr1, tr2, q0, q1, q2, q3,
                    v0, v1, v2, om0, om1, om2, Rm, In,
                    knv, muv, ldv, adv, inv_mass, mc0, mc1,
                    s_plane, out + (size_t)t * 7);
      }
      ++t; ++rrnd; --fullsteps;
      __syncthreads();   // s_plane(t) visible; s_red reusable
      continue;
    }

    // ---------- SCAN refresh ----------
    if (tid == 0) {
      s_reqw[0] = __float_as_uint(s_plane[0]);
      s_reqw[1] = __float_as_uint(s_plane[1]);
      s_reqw[2] = __float_as_uint(s_plane[2]);
      s_reqw[3] = __float_as_uint(s_plane[3]);
      s_reqw[4] = __float_as_uint(s_plane[4]);
      s_reqw[5] = __float_as_uint(s_plane[5]);
      s_reqw[6] = __float_as_uint(s_plane[6]);
      s_reqw[7] = __float_as_uint(s_plane[7]);
      s_reqw[8] = __float_as_uint(s_plane[3] + EPSB);
      s_reqw[9] = MODE_SCAN;
      #pragma unroll
      for (int k = 10; k < 16; ++k) s_reqw[k] = 0u;
      ar0 = s_plane[0]; ar1 = s_plane[1]; ar2 = s_plane[2];
      thr_r = s_plane[3] + EPSB;
    }
    __syncthreads();
    for (int i = tid; i < NREPR * 16; i += BLOCK)
      rec_store(req + i, rec_pack_u(s_reqw[i & 15], rrnd));
    // self scan
    scan_publish(xr0, xr1, xr2, s_plane[0], s_plane[1], s_plane[2],
                 s_plane[3] + EPSB, rrnd, cand, s_wc);
    // gather counts
    if (tid < GRID) {
      const u64* cp = cand + (size_t)tid * CSTRIDE;
      u64 r; int f = 0;
      for (;;) {
        r = rec_load(cp);
        if ((unsigned)(r >> 32) == rrnd) break;
        if ((++f & 15) == 0) __builtin_amdgcn_s_sleep(1);
      }
      s_cnt[tid] = (u32)r;
    }
    __syncthreads();
    if (tid == 0) {
      u32 total = 0, ovf = 0;
      for (int b = 0; b < GRID; ++b) {
        u32 c = s_cnt[b];
        if (c > CAP || total + c > CAPTOT) { ovf = 1; break; }
        for (u32 j = 0; j < c; ++j) cmap[total++] = ((u32)b << 16) | j;
      }
      s_total = total; s_act = ovf;
    }
    __syncthreads();
    if (s_act) {
      ++rrnd;
      fullsteps = 4;   // bounded fallback, rescan after 4 steps
      continue;
    }
    // load candidates into LDS (deterministic map order)
    {
      const int tot = (int)s_total;
      for (int c = tid; c < tot; c += BLOCK) {
        u32 e = cmap[c];
        const u64* dp = cand + (size_t)(e >> 16) * CSTRIDE + 1 + 3 * (size_t)(e & 0xFFFFu);
        u64 w0, w1, w2; int f = 0;
        for (;;) {
          w0 = rec_load(dp + 0); w1 = rec_load(dp + 1); w2 = rec_load(dp + 2);
          if (((unsigned)(w0 >> 32) == rrnd) && ((unsigned)(w1 >> 32) == rrnd) &&
              ((unsigned)(w2 >> 32) == rrnd)) break;
          if ((++f & 15) == 0) __builtin_amdgcn_s_sleep(1);
        }
        cx[c] = __uint_as_float((unsigned)w0);
        cy[c] = __uint_as_float((unsigned)w1);
        cz[c] = __uint_as_float((unsigned)w2);
      }
    }
    ++rrnd;
    __syncthreads();

    // ---------- local stepping on the candidate cache ----------
    for (;;) {
      const float A0 = s_plane[0], A1 = s_plane[1], A2 = s_plane[2], CAv = s_plane[3];
      const float B0 = s_plane[4], B1 = s_plane[5], B2 = s_plane[6], CBv = s_plane[7];
      float a0 = 0.f, a1 = 0.f, a2 = 0.f, a3 = 0.f;
      const int tot = (int)s_total;
      for (int c = tid; c < tot; c += BLOCK) {
        const float x0 = cx[c], x1 = cy[c], x2 = cz[c];
        const float da = x0*A0 + x1*A1 + x2*A2;
        const float db = x0*B0 + x1*B1 + x2*B2;
        if (da < CAv && db < CBv) { a0 += 1.f; a1 += x0; a2 += x1; a3 += x2; }
      }
      #pragma unroll
      for (int off = 32; off > 0; off >>= 1) {
        a0 += __shfl_down(a0, off, 64);
        a1 += __shfl_down(a1, off, 64);
        a2 += __shfl_down(a2, off, 64);
        a3 += __shfl_down(a3, off, 64);
      }
      if (lane == 0) {
        s_red[wid*4+0] = a0; s_red[wid*4+1] = a1;
        s_red[wid*4+2] = a2; s_red[wid*4+3] = a3;
      }
      __syncthreads();
      if (tid == 0) {
        float tn = s_red[0], tx = s_red[1], ty = s_red[2], tz = s_red[3];
        #pragma unroll
        for (int w = 1; w < NWAVES; ++w) {
          tn += s_red[w*4+0]; tx += s_red[w*4+1];
          ty += s_red[w*4+2]; tz += s_red[w*4+3];
        }
        leader_step(tn, tx, ty, tz, tr0, tr1, tr2, q0, q1, q2, q3,
                    v0, v1, v2, om0, om1, om2, Rm, In,
                    knv, muv, ldv, adv, inv_mass, mc0, mc1,
                    s_plane, out + (size_t)t * 7);
        // validity of the cache for the NEXT step's planes
        float d0 = s_plane[0] - ar0, d1 = s_plane[1] - ar1, d2 = s_plane[2] - ar2;
        float dA = sqrtf(d0*d0 + d1*d1 + d2*d2);
        int ok = (s_plane[3] + dA * maxX * 1.0001f + 1e-6f <= thr_r) ? 1 : 0;
        s_act = (t + 1 >= T) ? 2u : (ok ? 0u : 1u);
      }
      __syncthreads();
      ++t;
      if (s_act == 0u) continue;
      break;
    }
    // s_act == 2 -> t >= T -> DONE branch at loop top; s_act == 1 -> refresh
  }
}

extern "C" void kernel_launch(void* const* d_in, const int* in_sizes, int n_in,
                              void* d_out, int out_size, void* d_ws, size_t ws_size,
                              hipStream_t stream) {
  const float* x   = (const float*)d_in[0];
  const float* mc  = (const float*)d_in[1];
  const float* itr = (const float*)d_in[2];
  const float* iq  = (const float*)d_in[3];
  const float* iv  = (const float*)d_in[4];
  const float* kn  = (const float*)d_in[5];
  const float* mu  = (const float*)d_in[6];
  const float* ldp = (const float*)d_in[7];
  const float* adp = (const float*)d_in[8];
  float* out = (float*)d_out;
  u64* ws  = (u64*)d_ws;
  int N = in_sizes[0] / 3;
  int T = out_size / 7;

  const int dyn_lds = 4 * CAPTOT * 4;   // 64 KB: cx,cy,cz,map
  hipFuncSetAttribute((const void*)sim_kernel,
                      hipFuncAttributeMaxDynamicSharedMemorySize, dyn_lds);

  void* args[] = {(void*)&x, (void*)&mc, (void*)&itr, (void*)&iq, (void*)&iv,
                  (void*)&kn, (void*)&mu, (void*)&ldp, (void*)&adp,
                  (void*)&out, (void*)&ws, (void*)&N, (void*)&T};
  // cooperative launch kept ONLY for the co-residency guarantee
  hipLaunchCooperativeKernel((void*)sim_kernel, dim3(GRID), dim3(BLOCK),
                             args, dyn_lds, stream);
}